// Round 1
// baseline (325.918 us; speedup 1.0000x reference)
//
#include <hip/hip_runtime.h>
#include <hip/hip_bf16.h>
#include <stdint.h>

#define NH 12
#define DH 64
#define CC 768
#define NTOK 197
#define PFX 10
#define MKV 207
#define BB 64
#define MROWS (BB * NTOK)   // 12608
#define KV_PAD 208          // 13 * 16
#define KV_PAD2 224         // 7 * 32

typedef __attribute__((__ext_vector_type__(8))) short bf16x8;
typedef __attribute__((__ext_vector_type__(4))) float f32x4;

__device__ __forceinline__ ushort f2bf(float f) {
    union { float f; uint32_t u; } x; x.f = f;
    uint32_t u = x.u;
    return (ushort)((u + 0x7fffu + ((u >> 16) & 1u)) >> 16);
}

// ---------------- convert fp32 -> bf16 (vectorized) ----------------
__global__ void cvt_bf16(const float* __restrict__ src, ushort* __restrict__ dst, int n4) {
    int i = blockIdx.x * 256 + threadIdx.x;
    if (i >= n4) return;
    float4 v = reinterpret_cast<const float4*>(src)[i];
    ushort4 o = make_ushort4(f2bf(v.x), f2bf(v.y), f2bf(v.z), f2bf(v.w));
    reinterpret_cast<ushort4*>(dst)[i] = o;
}

// ---------------- prompt prefix scatter ----------------
// prompt [B,2,P,H,D] fp32 -> kbuf[b,h,p,d] bf16 ; vt[b,h,d,p] bf16
__global__ void prompt_scatter(const float* __restrict__ prompt,
                               ushort* __restrict__ kbuf, ushort* __restrict__ vt) {
    int i = blockIdx.x * 256 + threadIdx.x;
    if (i >= BB * 2 * PFX * NH * DH) return;
    int d = i & 63;
    int h = (i >> 6) % NH;
    int p = (i / (64 * NH)) % PFX;
    int s = (i / (64 * NH * PFX)) & 1;
    int b = i / (64 * NH * PFX * 2);
    ushort val = f2bf(prompt[i]);
    int bh = b * NH + h;
    if (s == 0) kbuf[(bh * KV_PAD + p) * DH + d] = val;
    else        vt[(bh * DH + d) * KV_PAD2 + p] = val;
}

// ---------------- GEMM core macro pieces ----------------
// C[M,N] = A[M,K] @ B[N,K]^T, A/B bf16 row-major, 128x128 tile, BK=32, 4 waves.

#define GEMM_BODY(A_, B_, KDIM, NCHECK)                                               \
    __shared__ __align__(16) ushort Alds[128][40];                                    \
    __shared__ __align__(16) ushort Blds[128][40];                                    \
    const int tid  = threadIdx.x;                                                     \
    const int lane = tid & 63;                                                        \
    const int wave = tid >> 6;                                                        \
    const int wm = wave >> 1, wn = wave & 1;                                          \
    const int g = lane >> 4, lr = lane & 15;                                          \
    const int row0 = blockIdx.x * 128;                                                \
    const int col0 = blockIdx.y * 128;                                                \
    const int lrow = tid >> 1;                                                        \
    const int lseg = (tid & 1) * 16;                                                  \
    f32x4 acc[4][4] = {};                                                             \
    for (int k0 = 0; k0 < (KDIM); k0 += 32) {                                         \
        int gr = row0 + lrow;                                                         \
        int4 a0 = make_int4(0,0,0,0), a1 = make_int4(0,0,0,0);                        \
        if (gr < MROWS) {                                                             \
            const int4* pa = reinterpret_cast<const int4*>(&(A_)[(size_t)gr*(KDIM) + k0 + lseg]); \
            a0 = pa[0]; a1 = pa[1];                                                   \
        }                                                                             \
        const int4* pb = reinterpret_cast<const int4*>(&(B_)[(size_t)(col0+lrow)*(KDIM) + k0 + lseg]); \
        int4 b0 = pb[0], b1 = pb[1];                                                  \
        __syncthreads();                                                              \
        *reinterpret_cast<int4*>(&Alds[lrow][lseg])     = a0;                         \
        *reinterpret_cast<int4*>(&Alds[lrow][lseg + 8]) = a1;                         \
        *reinterpret_cast<int4*>(&Blds[lrow][lseg])     = b0;                         \
        *reinterpret_cast<int4*>(&Blds[lrow][lseg + 8]) = b1;                         \
        __syncthreads();                                                              \
        bf16x8 af[4], bfr[4];                                                         \
        _Pragma("unroll")                                                             \
        for (int i = 0; i < 4; ++i)                                                   \
            af[i] = *reinterpret_cast<const bf16x8*>(&Alds[wm*64 + i*16 + lr][g*8]);  \
        _Pragma("unroll")                                                             \
        for (int i = 0; i < 4; ++i)                                                   \
            bfr[i] = *reinterpret_cast<const bf16x8*>(&Blds[wn*64 + i*16 + lr][g*8]); \
        _Pragma("unroll")                                                             \
        for (int mi = 0; mi < 4; ++mi)                                                \
            _Pragma("unroll")                                                         \
            for (int ni = 0; ni < 4; ++ni)                                            \
                acc[mi][ni] = __builtin_amdgcn_mfma_f32_16x16x32_bf16(af[mi], bfr[ni], acc[mi][ni], 0, 0, 0); \
    }

// GEMM1: X[12608,768] @ qkv_w[2304,768]^T -> scatter q/k/vt (bf16)
__global__ __launch_bounds__(256) void gemm_qkv(const ushort* __restrict__ A,
                                                const ushort* __restrict__ Bw,
                                                ushort* __restrict__ qbuf,
                                                ushort* __restrict__ kbuf,
                                                ushort* __restrict__ vt) {
    GEMM_BODY(A, Bw, CC, 1)
    #pragma unroll
    for (int ni = 0; ni < 4; ++ni) {
        int f = col0 + wn * 64 + ni * 16 + lr;     // 0..2303
        int s   = f / CC;
        int rem = f - s * CC;
        int h = rem >> 6, d = rem & 63;
        #pragma unroll
        for (int mi = 0; mi < 4; ++mi) {
            #pragma unroll
            for (int rr = 0; rr < 4; ++rr) {
                int r = row0 + wm * 64 + mi * 16 + g * 4 + rr;
                if (r >= MROWS) continue;
                int b = r / NTOK;
                int n = r - b * NTOK;
                ushort val = f2bf(acc[mi][ni][rr]);
                int bh = b * NH + h;
                if (s == 0)      qbuf[(bh * KV_PAD + n) * DH + d] = val;
                else if (s == 1) kbuf[(bh * KV_PAD + n + PFX) * DH + d] = val;
                else             vt[(bh * DH + d) * KV_PAD2 + n + PFX] = val;
            }
        }
    }
}

// GEMM2: aout[12608,768] @ proj_w[768,768]^T + bias -> out fp32
__global__ __launch_bounds__(256) void gemm_proj(const ushort* __restrict__ A,
                                                 const ushort* __restrict__ Bw,
                                                 const float* __restrict__ bias,
                                                 float* __restrict__ out) {
    GEMM_BODY(A, Bw, CC, 1)
    #pragma unroll
    for (int ni = 0; ni < 4; ++ni) {
        int o = col0 + wn * 64 + ni * 16 + lr;
        float bs = bias[o];
        #pragma unroll
        for (int mi = 0; mi < 4; ++mi) {
            #pragma unroll
            for (int rr = 0; rr < 4; ++rr) {
                int r = row0 + wm * 64 + mi * 16 + g * 4 + rr;
                if (r >= MROWS) continue;
                out[(size_t)r * CC + o] = acc[mi][ni][rr] + bs;
            }
        }
    }
}

// ---------------- attention ----------------
// 1 wave per (q-tile of 16 rows, b*h). Swapped QK^T: S^T = mfma(K, Q).
// Lane (g,lr): holds S^T[kv = t*16 + g*4 + rr][q = qt*16 + lr].
__global__ __launch_bounds__(64) void attn(const ushort* __restrict__ qbuf,
                                           const ushort* __restrict__ kbuf,
                                           const ushort* __restrict__ vt,
                                           ushort* __restrict__ aout) {
    __shared__ __align__(16) ushort Plds[16][232];
    const int lane = threadIdx.x;
    const int g = lane >> 4, lr = lane & 15;
    const int qt = blockIdx.x;           // 0..12
    const int bh = blockIdx.y;           // 0..767
    const int b = bh / NH;
    const int h = bh - b * NH;
    const ushort* Q  = qbuf + (size_t)bh * KV_PAD * DH;
    const ushort* Kb = kbuf + (size_t)bh * KV_PAD * DH;
    const ushort* V  = vt   + (size_t)bh * DH * KV_PAD2;

    bf16x8 qf[2];
    #pragma unroll
    for (int kc = 0; kc < 2; ++kc)
        qf[kc] = *reinterpret_cast<const bf16x8*>(&Q[(qt * 16 + lr) * DH + kc * 32 + g * 8]);

    f32x4 s[13];
    #pragma unroll
    for (int t = 0; t < 13; ++t) {
        f32x4 a = {};
        #pragma unroll
        for (int kc = 0; kc < 2; ++kc) {
            bf16x8 kf = *reinterpret_cast<const bf16x8*>(&Kb[(t * 16 + lr) * DH + kc * 32 + g * 8]);
            a = __builtin_amdgcn_mfma_f32_16x16x32_bf16(kf, qf[kc], a, 0, 0, 0);
        }
        s[t] = a;
    }

    // mask pad kv rows, row-max
    float m = -1e30f;
    #pragma unroll
    for (int t = 0; t < 13; ++t) {
        #pragma unroll
        for (int rr = 0; rr < 4; ++rr) {
            int kv = t * 16 + g * 4 + rr;
            float v = (kv < MKV) ? s[t][rr] : -1e30f;
            s[t][rr] = v;
            m = fmaxf(m, v);
        }
    }
    m = fmaxf(m, __shfl_xor(m, 16));
    m = fmaxf(m, __shfl_xor(m, 32));

    const float cs = 0.125f * 1.4426950408889634f;  // scale * log2(e)
    float sum = 0.f;
    #pragma unroll
    for (int t = 0; t < 13; ++t) {
        #pragma unroll
        for (int rr = 0; rr < 4; ++rr) {
            float p = exp2f((s[t][rr] - m) * cs);
            s[t][rr] = p;
            sum += p;
        }
    }
    sum += __shfl_xor(sum, 16);
    sum += __shfl_xor(sum, 32);
    float inv = 1.0f / sum;

    // zero P pad (kv 208..223)
    {
        int row = lane >> 2;
        int col = 208 + (lane & 3) * 4;
        *reinterpret_cast<ushort4*>(&Plds[row][col]) = make_ushort4(0, 0, 0, 0);
    }
    #pragma unroll
    for (int t = 0; t < 13; ++t) {
        #pragma unroll
        for (int rr = 0; rr < 4; ++rr)
            Plds[lr][t * 16 + g * 4 + rr] = f2bf(s[t][rr] * inv);
    }
    __syncthreads();

    // PV: out^T = mfma(Vt, P)  -> lane holds out[d = dt*16 + g*4 + rr][q = qt*16 + lr]
    const int q = qt * 16 + lr;
    #pragma unroll
    for (int dt = 0; dt < 4; ++dt) {
        f32x4 o = {};
        #pragma unroll
        for (int kc = 0; kc < 7; ++kc) {
            bf16x8 vf = *reinterpret_cast<const bf16x8*>(&V[(dt * 16 + lr) * KV_PAD2 + kc * 32 + g * 8]);
            bf16x8 pf = *reinterpret_cast<const bf16x8*>(&Plds[lr][kc * 32 + g * 8]);
            o = __builtin_amdgcn_mfma_f32_16x16x32_bf16(vf, pf, o, 0, 0, 0);
        }
        if (q < NTOK) {
            ushort4 st = make_ushort4(f2bf(o[0]), f2bf(o[1]), f2bf(o[2]), f2bf(o[3]));
            int r = b * NTOK + q;
            *reinterpret_cast<ushort4*>(&aout[(size_t)r * CC + h * 64 + dt * 16 + g * 4]) = st;
        }
    }
}

// ---------------- launch ----------------
extern "C" void kernel_launch(void* const* d_in, const int* in_sizes, int n_in,
                              void* d_out, int out_size, void* d_ws, size_t ws_size,
                              hipStream_t stream) {
    const float* x      = (const float*)d_in[0];
    const float* prompt = (const float*)d_in[1];
    const float* qkv_w  = (const float*)d_in[2];
    const float* proj_w = (const float*)d_in[3];
    const float* proj_b = (const float*)d_in[4];
    float* out = (float*)d_out;

    char* ws = (char*)d_ws;
    ushort* Xb = (ushort*)(ws + 0);          // 12608*768*2      = 19,365,888
    ushort* Wq = (ushort*)(ws + 19365888);   // 2304*768*2       =  3,538,944
    ushort* Wp = (ushort*)(ws + 22904832);   // 768*768*2        =  1,179,648
    ushort* qb = (ushort*)(ws + 24084480);   // 768*208*64*2     = 20,447,232
    ushort* kb = (ushort*)(ws + 44531712);   // 768*208*64*2     = 20,447,232
    ushort* vt = (ushort*)(ws + 64978944);   // 768*64*224*2     = 22,020,096
    ushort* ao = (ushort*)(ws + 86999040);   // 12608*768*2      = 19,365,888
    // total 106,364,928 bytes

    cvt_bf16<<<dim3((MROWS * CC / 4 + 255) / 256), 256, 0, stream>>>(x, Xb, MROWS * CC / 4);
    cvt_bf16<<<dim3((3 * CC * CC / 4 + 255) / 256), 256, 0, stream>>>(qkv_w, Wq, 3 * CC * CC / 4);
    cvt_bf16<<<dim3((CC * CC / 4 + 255) / 256), 256, 0, stream>>>(proj_w, Wp, CC * CC / 4);
    prompt_scatter<<<dim3((BB * 2 * PFX * NH * DH + 255) / 256), 256, 0, stream>>>(prompt, kb, vt);

    gemm_qkv<<<dim3(99, 18), 256, 0, stream>>>(Xb, Wq, qb, kb, vt);
    attn<<<dim3(13, BB * NH), 64, 0, stream>>>(qb, kb, vt, ao);
    gemm_proj<<<dim3(99, 6), 256, 0, stream>>>(ao, Wp, proj_b, out);
}

// Round 3
// 314.584 us; speedup vs baseline: 1.0360x; 1.0360x over previous
//
#include <hip/hip_runtime.h>
#include <hip/hip_bf16.h>
#include <stdint.h>

#define NH 12
#define DH 64
#define CC 768
#define NTOK 197
#define PFX 10
#define MKV 207
#define BB 64
#define MROWS (BB * NTOK)   // 12608
#define MPAD (99 * 128)     // 12672 padded rows so global_load_lds never faults
#define KV_PAD 208          // 13 * 16
#define KV_PAD2 224         // 7 * 32

typedef __attribute__((__ext_vector_type__(8))) short bf16x8;
typedef __attribute__((__ext_vector_type__(4))) float f32x4;

__device__ __forceinline__ ushort f2bf(float f) {
    union { float f; uint32_t u; } x; x.f = f;
    uint32_t u = x.u;
    return (ushort)((u + 0x7fffu + ((u >> 16) & 1u)) >> 16);
}

__device__ __forceinline__ void gload_lds16(const void* g, void* l) {
    __builtin_amdgcn_global_load_lds(
        (const __attribute__((address_space(1))) void*)g,
        (__attribute__((address_space(3))) void*)l, 16, 0, 0);
}

// ---------------- convert fp32 -> bf16 (vectorized) ----------------
__global__ void cvt_bf16(const float* __restrict__ src, ushort* __restrict__ dst, int n4) {
    int i = blockIdx.x * 256 + threadIdx.x;
    if (i >= n4) return;
    float4 v = reinterpret_cast<const float4*>(src)[i];
    ushort4 o = make_ushort4(f2bf(v.x), f2bf(v.y), f2bf(v.z), f2bf(v.w));
    reinterpret_cast<ushort4*>(dst)[i] = o;
}

// ---------------- prompt prefix scatter ----------------
// prompt [B,2,P,H,D] fp32 -> kbuf[b,h,p,d] bf16 ; vt[b,h,d,p] bf16
__global__ void prompt_scatter(const float* __restrict__ prompt,
                               ushort* __restrict__ kbuf, ushort* __restrict__ vt) {
    int i = blockIdx.x * 256 + threadIdx.x;
    if (i >= BB * 2 * PFX * NH * DH) return;
    int d = i & 63;
    int h = (i >> 6) % NH;
    int p = (i / (64 * NH)) % PFX;
    int s = (i / (64 * NH * PFX)) & 1;
    int b = i / (64 * NH * PFX * 2);
    ushort val = f2bf(prompt[i]);
    int bh = b * NH + h;
    if (s == 0) kbuf[(bh * KV_PAD + p) * DH + d] = val;
    else        vt[(bh * DH + d) * KV_PAD2 + p] = val;
}

// ---------------- GEMM core (m97 structure) ----------------
// C[M,N] = A[M,K] @ B[N,K]^T, bf16 row-major both, 128x128 tile, BK=32,
// 4 waves, global_load_lds width-16 staging into linear [128][32] LDS.
// A must have >= row0+128 readable rows (MPAD padding).

#define GEMM_MAIN(A_, B_, KDIM)                                                      \
    __shared__ __align__(16) ushort Alds[128 * 32];                                  \
    __shared__ __align__(16) ushort Blds[128 * 32];                                  \
    const int tid  = threadIdx.x;                                                    \
    const int lane = tid & 63;                                                       \
    const int wave = tid >> 6;                                                       \
    const int wm = wave >> 1, wn = wave & 1;                                         \
    const int g = lane >> 4, lr = lane & 15;                                         \
    const int row0 = blockIdx.x * 128;                                               \
    const int col0 = blockIdx.y * 128;                                               \
    const int srow = lane >> 2;                                                      \
    const int scol = (lane & 3) * 8;                                                 \
    const ushort* gA0 = &(A_)[(size_t)(row0 + wave * 16 + srow) * (KDIM) + scol];    \
    const ushort* gA1 = gA0 + (size_t)64 * (KDIM);                                   \
    const ushort* gB0 = &(B_)[(size_t)(col0 + wave * 16 + srow) * (KDIM) + scol];    \
    const ushort* gB1 = gB0 + (size_t)64 * (KDIM);                                   \
    ushort* lA0 = &Alds[(wave * 16) * 32];                                           \
    ushort* lA1 = &Alds[(64 + wave * 16) * 32];                                      \
    ushort* lB0 = &Blds[(wave * 16) * 32];                                           \
    ushort* lB1 = &Blds[(64 + wave * 16) * 32];                                      \
    f32x4 acc[4][4] = {};                                                            \
    for (int k0 = 0; k0 < (KDIM); k0 += 32) {                                        \
        gload_lds16(gA0 + k0, lA0);                                                  \
        gload_lds16(gA1 + k0, lA1);                                                  \
        gload_lds16(gB0 + k0, lB0);                                                  \
        gload_lds16(gB1 + k0, lB1);                                                  \
        __syncthreads();   /* compiler drains vmcnt before barrier: staging done */  \
        bf16x8 af[4], bfr[4];                                                        \
        _Pragma("unroll")                                                            \
        for (int i = 0; i < 4; ++i)                                                  \
            af[i] = *reinterpret_cast<const bf16x8*>(&Alds[(wm * 64 + i * 16 + lr) * 32 + g * 8]); \
        _Pragma("unroll")                                                            \
        for (int i = 0; i < 4; ++i)                                                  \
            bfr[i] = *reinterpret_cast<const bf16x8*>(&Blds[(wn * 64 + i * 16 + lr) * 32 + g * 8]); \
        _Pragma("unroll")                                                            \
        for (int mi = 0; mi < 4; ++mi)                                               \
            _Pragma("unroll")                                                        \
            for (int ni = 0; ni < 4; ++ni)                                           \
                acc[mi][ni] = __builtin_amdgcn_mfma_f32_16x16x32_bf16(af[mi], bfr[ni], acc[mi][ni], 0, 0, 0); \
        __syncthreads();                                                             \
    }

// GEMM1: X[12608,768] @ qkv_w[2304,768]^T -> scatter q/k/vt (bf16)
__global__ __launch_bounds__(256) void gemm_qkv(const ushort* __restrict__ A,
                                                const ushort* __restrict__ Bw,
                                                ushort* __restrict__ qbuf,
                                                ushort* __restrict__ kbuf,
                                                ushort* __restrict__ vt) {
    GEMM_MAIN(A, Bw, CC)
    #pragma unroll
    for (int ni = 0; ni < 4; ++ni) {
        int f = col0 + wn * 64 + ni * 16 + lr;     // 0..2303
        int s   = f / CC;
        int rem = f - s * CC;
        int h = rem >> 6, d = rem & 63;
        #pragma unroll
        for (int mi = 0; mi < 4; ++mi) {
            #pragma unroll
            for (int rr = 0; rr < 4; ++rr) {
                int r = row0 + wm * 64 + mi * 16 + g * 4 + rr;
                if (r >= MROWS) continue;
                int b = r / NTOK;
                int n = r - b * NTOK;
                ushort val = f2bf(acc[mi][ni][rr]);
                int bh = b * NH + h;
                if (s == 0)      qbuf[(bh * KV_PAD + n) * DH + d] = val;
                else if (s == 1) kbuf[(bh * KV_PAD + n + PFX) * DH + d] = val;
                else             vt[(bh * DH + d) * KV_PAD2 + n + PFX] = val;
            }
        }
    }
}

// GEMM2: aout[12608,768] @ proj_w[768,768]^T + bias -> out fp32
__global__ __launch_bounds__(256) void gemm_proj(const ushort* __restrict__ A,
                                                 const ushort* __restrict__ Bw,
                                                 const float* __restrict__ bias,
                                                 float* __restrict__ out) {
    GEMM_MAIN(A, Bw, CC)
    #pragma unroll
    for (int ni = 0; ni < 4; ++ni) {
        int o = col0 + wn * 64 + ni * 16 + lr;
        float bs = bias[o];
        #pragma unroll
        for (int mi = 0; mi < 4; ++mi) {
            #pragma unroll
            for (int rr = 0; rr < 4; ++rr) {
                int r = row0 + wm * 64 + mi * 16 + g * 4 + rr;
                if (r >= MROWS) continue;
                out[(size_t)r * CC + o] = acc[mi][ni][rr] + bs;
            }
        }
    }
}

// ---------------- attention ----------------
// 1 wave per (q-tile of 16 rows, b*h). Swapped QK^T: S^T = mfma(K, Q).
// Lane (g,lr): holds S^T[kv = t*16 + g*4 + rr][q = qt*16 + lr].
__global__ __launch_bounds__(64) void attn(const ushort* __restrict__ qbuf,
                                           const ushort* __restrict__ kbuf,
                                           const ushort* __restrict__ vt,
                                           ushort* __restrict__ aout) {
    __shared__ __align__(16) ushort Plds[16][232];
    const int lane = threadIdx.x;
    const int g = lane >> 4, lr = lane & 15;
    const int qt = blockIdx.x;           // 0..12
    const int bh = blockIdx.y;           // 0..767
    const int b = bh / NH;
    const int h = bh - b * NH;
    const ushort* Q  = qbuf + (size_t)bh * KV_PAD * DH;
    const ushort* Kb = kbuf + (size_t)bh * KV_PAD * DH;
    const ushort* V  = vt   + (size_t)bh * DH * KV_PAD2;

    bf16x8 qf[2];
    #pragma unroll
    for (int kc = 0; kc < 2; ++kc)
        qf[kc] = *reinterpret_cast<const bf16x8*>(&Q[(qt * 16 + lr) * DH + kc * 32 + g * 8]);

    f32x4 s[13];
    #pragma unroll
    for (int t = 0; t < 13; ++t) {
        f32x4 a = {};
        #pragma unroll
        for (int kc = 0; kc < 2; ++kc) {
            bf16x8 kf = *reinterpret_cast<const bf16x8*>(&Kb[(t * 16 + lr) * DH + kc * 32 + g * 8]);
            a = __builtin_amdgcn_mfma_f32_16x16x32_bf16(kf, qf[kc], a, 0, 0, 0);
        }
        s[t] = a;
    }

    // mask pad kv rows, row-max
    float m = -1e30f;
    #pragma unroll
    for (int t = 0; t < 13; ++t) {
        #pragma unroll
        for (int rr = 0; rr < 4; ++rr) {
            int kv = t * 16 + g * 4 + rr;
            float v = (kv < MKV) ? s[t][rr] : -1e30f;
            s[t][rr] = v;
            m = fmaxf(m, v);
        }
    }
    m = fmaxf(m, __shfl_xor(m, 16));
    m = fmaxf(m, __shfl_xor(m, 32));

    const float cs = 0.125f * 1.4426950408889634f;  // scale * log2(e)
    float sum = 0.f;
    #pragma unroll
    for (int t = 0; t < 13; ++t) {
        #pragma unroll
        for (int rr = 0; rr < 4; ++rr) {
            float p = exp2f((s[t][rr] - m) * cs);
            s[t][rr] = p;
            sum += p;
        }
    }
    sum += __shfl_xor(sum, 16);
    sum += __shfl_xor(sum, 32);
    float inv = 1.0f / sum;

    // zero P pad (kv 208..223)
    {
        int row = lane >> 2;
        int col = 208 + (lane & 3) * 4;
        *reinterpret_cast<ushort4*>(&Plds[row][col]) = make_ushort4(0, 0, 0, 0);
    }
    #pragma unroll
    for (int t = 0; t < 13; ++t) {
        #pragma unroll
        for (int rr = 0; rr < 4; ++rr)
            Plds[lr][t * 16 + g * 4 + rr] = f2bf(s[t][rr] * inv);
    }
    __syncthreads();

    // PV: out^T = mfma(Vt, P)  -> lane holds out[d = dt*16 + g*4 + rr][q = qt*16 + lr]
    const int q = qt * 16 + lr;
    #pragma unroll
    for (int dt = 0; dt < 4; ++dt) {
        f32x4 o = {};
        #pragma unroll
        for (int kc = 0; kc < 7; ++kc) {
            bf16x8 vf = *reinterpret_cast<const bf16x8*>(&V[(dt * 16 + lr) * KV_PAD2 + kc * 32 + g * 8]);
            bf16x8 pf = *reinterpret_cast<const bf16x8*>(&Plds[lr][kc * 32 + g * 8]);
            o = __builtin_amdgcn_mfma_f32_16x16x32_bf16(vf, pf, o, 0, 0, 0);
        }
        if (q < NTOK) {
            ushort4 st = make_ushort4(f2bf(o[0]), f2bf(o[1]), f2bf(o[2]), f2bf(o[3]));
            int r = b * NTOK + q;
            *reinterpret_cast<ushort4*>(&aout[(size_t)r * CC + h * 64 + dt * 16 + g * 4]) = st;
        }
    }
}

// ---------------- launch ----------------
extern "C" void kernel_launch(void* const* d_in, const int* in_sizes, int n_in,
                              void* d_out, int out_size, void* d_ws, size_t ws_size,
                              hipStream_t stream) {
    const float* x      = (const float*)d_in[0];
    const float* prompt = (const float*)d_in[1];
    const float* qkv_w  = (const float*)d_in[2];
    const float* proj_w = (const float*)d_in[3];
    const float* proj_b = (const float*)d_in[4];
    float* out = (float*)d_out;

    char* ws = (char*)d_ws;
    ushort* Xb = (ushort*)(ws + 0);          // MPAD*768*2       = 19,464,192
    ushort* Wq = (ushort*)(ws + 19464192);   // 2304*768*2       =  3,538,944
    ushort* Wp = (ushort*)(ws + 23003136);   // 768*768*2        =  1,179,648
    ushort* qb = (ushort*)(ws + 24182784);   // 768*208*64*2     = 20,447,232
    ushort* kb = (ushort*)(ws + 44630016);   // 768*208*64*2     = 20,447,232
    ushort* vt = (ushort*)(ws + 65077248);   // 768*64*224*2     = 22,020,096
    ushort* ao = (ushort*)(ws + 87097344);   // MPAD*768*2       = 19,464,192
    // total 106,561,536 bytes

    cvt_bf16<<<dim3((MROWS * CC / 4 + 255) / 256), 256, 0, stream>>>(x, Xb, MROWS * CC / 4);
    cvt_bf16<<<dim3((3 * CC * CC / 4 + 255) / 256), 256, 0, stream>>>(qkv_w, Wq, 3 * CC * CC / 4);
    cvt_bf16<<<dim3((CC * CC / 4 + 255) / 256), 256, 0, stream>>>(proj_w, Wp, CC * CC / 4);
    prompt_scatter<<<dim3((BB * 2 * PFX * NH * DH + 255) / 256), 256, 0, stream>>>(prompt, kb, vt);

    gemm_qkv<<<dim3(99, 18), 256, 0, stream>>>(Xb, Wq, qb, kb, vt);
    attn<<<dim3(13, BB * NH), 64, 0, stream>>>(qb, kb, vt, ao);
    gemm_proj<<<dim3(99, 6), 256, 0, stream>>>(ao, Wp, proj_b, out);
}